// Round 17
// baseline (96.405 us; speedup 1.0000x reference)
//
#include <hip/hip_runtime.h>
#include <hip/hip_fp16.h>

// MLPKANlayer: out[b][o] = sum_i g_n(x[b,i]), n = i*128+o,
//   g_n(x) = y_n(x)*ss_n + x*rs_n  (1->5->5->1 SiLU MLP). f32 in/out.
//
// R17 = R16 + clean occupancy fix (no atomics): R14/R16's residency cap was
// the GRID (512 blocks = 2/CU), not LDS. Now block = (o, 256 rows) x 512 thr;
// waves 0-3 eval i<64, waves 4-7 eval i>=64 against the SAME 48-KiB staged
// table; i-halves combine via 1-KiB in-block LDS reduce. Grid 1024 x 8 waves
// = 8192 waves, LDS 49 KiB -> 3 blocks/CU = 24 waves/CU (+50% TLP).
// R15 lesson: atomic combine costs more than TLP gains -> in-block reduce.
// R13 lesson: table traffic stays in LDS. Harness floor ~63 us is fixed.

constexpr int IN_SZ = 128, OUT_SZ = 128, BATCH = 2048, NSUB = IN_SZ * OUT_SZ;
constexpr int NSEG = 96;                       // segments; 97 knot values
constexpr float XMIN = -4.5f, XRANGE = 9.0f;
constexpr float STEP = XRANGE / (float)NSEG;
constexpr float INVH = (float)NSEG / XRANGE;   // 10.6667
constexpr float UOFF = -XMIN * INVH;           // 48

__device__ __forceinline__ float silu_f(float z) {
  float t = __builtin_amdgcn_exp2f(z * -1.44269504088896f);   // exp(-z)
  return z * __builtin_amdgcn_rcpf(1.0f + t);
}

// ---- k1 prep: build table (blocks < 8192) + pack-transpose x (>= 8192) -----
// Build: 2 subnets x 128 lanes (k = 0..96 active); subnet wave-uniform ->
// weights are s_loads. tbl[(o*128+i)*96+k] = half2(g(x_k), g(x_{k+1})-g(x_k))
// Transpose: xTP[g][b][4] = x[b][4g..4g+3]  (float4-coalesced both sides).
__global__ __launch_bounds__(256) void prep(
    const float* __restrict__ x,
    const float* __restrict__ w0, const float* __restrict__ b0,
    const float* __restrict__ w1, const float* __restrict__ b1,
    const float* __restrict__ w2, const float* __restrict__ b2,
    const float* __restrict__ ss, const float* __restrict__ rs,
    __half2* __restrict__ tbl, float4* __restrict__ xTP) {
  __shared__ float smem[64 * 65];
  const int tid = threadIdx.x;
  const int blk = blockIdx.x;

  if (blk < NSUB / 2) {
    float (*gv)[128] = (float (*)[128])smem;
    const int sl = __builtin_amdgcn_readfirstlane(tid >> 7);  // 0..1 uniform
    const int k  = tid & 127;
    const int n  = blk * 2 + sl;

    if (k <= NSEG) {
      const float xk = XMIN + (float)k * STEP;
      float h1[5], h2[5];
#pragma unroll
      for (int j = 0; j < 5; ++j)
        h1[j] = silu_f(fmaf(w0[n * 5 + j], xk, b0[n * 5 + j]));
#pragma unroll
      for (int j = 0; j < 5; ++j) {
        float z = b1[n * 5 + j];
#pragma unroll
        for (int kk = 0; kk < 5; ++kk)
          z = fmaf(w1[n * 25 + j * 5 + kk], h1[kk], z);
        h2[j] = silu_f(z);
      }
      float y = b2[n];
#pragma unroll
      for (int kk = 0; kk < 5; ++kk) y = fmaf(w2[n * 5 + kk], h2[kk], y);
      gv[sl][k] = fmaf(y, ss[n], xk * rs[n]);
    }
    __syncthreads();
    if (k < NSEG) {
      float a = gv[sl][k];
      float s = gv[sl][k + 1] - a;
      int o = n & (OUT_SZ - 1), i = n >> 7;
      tbl[(size_t)(o * IN_SZ + i) * NSEG + k] = __floats2half2_rn(a, s);
    }
  } else {
    // pack-transpose: 64(b) x 64(i) tile
    float (*tile)[65] = (float (*)[65])smem;
    const int t   = blk - NSUB / 2;              // 0..63
    const int b0t = (t & 31) * 64;
    const int i0  = (t >> 5) * 64;
    const int l = tid & 63, w = tid >> 6;        // l = b-lane, w = 0..3
#pragma unroll
    for (int r = 0; r < 16; ++r) {
      int row = w + 4 * r;                       // b-local
      tile[row][l] = x[(size_t)(b0t + row) * IN_SZ + i0 + l];
    }
    __syncthreads();
    // write float4 per (g, b): lanes over b -> 1024 B contiguous wave-store
#pragma unroll
    for (int r = 0; r < 4; ++r) {
      int g = w + 4 * r;                         // i-group local, 0..15
      float4 v = make_float4(tile[l][4 * g], tile[l][4 * g + 1],
                             tile[l][4 * g + 2], tile[l][4 * g + 3]);
      xTP[(size_t)(i0 / 4 + g) * BATCH + b0t + l] = v;
    }
  }
}

// ---- k2 main: block = (o, 256 rows) x 512 thr; i split across wave-halves --
__global__ __launch_bounds__(512) void mlp_tbl_lds(
    const float4* __restrict__ xTP, const __half2* __restrict__ tbl,
    float* __restrict__ out) {
  __shared__ __half2 ts[IN_SZ * NSEG];   // 48 KiB table
  __shared__ float red[256];             // +1 KiB reduce scratch

  const int tid   = threadIdx.x;
  const int o     = blockIdx.x & (OUT_SZ - 1);   // same-o -> same XCD
  const int chunk = blockIdx.x >> 7;             // 0..7

  // stage o-slice: 48 KiB = 3072 uint4, 6 per thread, coalesced
  {
    const uint4* __restrict__ s4 =
        (const uint4*)(tbl + (size_t)o * IN_SZ * NSEG);
    uint4* d4 = (uint4*)ts;
#pragma unroll
    for (int r = 0; r < 6; ++r) d4[tid + 512 * r] = s4[tid + 512 * r];
  }
  __syncthreads();

  const int rl  = tid & 255;                     // row-local, 0..255
  const int ih  = tid >> 8;                      // i-half (wave-uniform)
  const int row = chunk * 256 + rl;              // batch row
  const float4* __restrict__ xcol = xTP + (size_t)(ih * 16) * BATCH + row;

  float acc0 = 0.0f, acc1 = 0.0f, acc2 = 0.0f, acc3 = 0.0f;
#pragma unroll 4
  for (int g = 0; g < 16; ++g) {                 // 16 groups x 4 i = 64 evals
    float4 xv = xcol[(size_t)g * BATCH];         // 4 i-values, one dwordx4
    float xs[4] = { xv.x, xv.y, xv.z, xv.w };
#pragma unroll
    for (int j = 0; j < 4; ++j) {
      const int il = (ih * 16 + g) * 4 + j;      // absolute i
      float u  = fmaf(xs[j], INVH, UOFF);
      float fi = __builtin_amdgcn_fmed3f(floorf(u), 0.0f, (float)(NSEG - 1));
      float f  = u - fi;                         // unclamped -> extrapolate
      __half2 h = ts[il * NSEG + (int)fi];       // offset il*384 folds to imm
      float lo = __half2float(__low2half(h));
      float hi = __half2float(__high2half(h));
      float t  = fmaf(hi, f, lo);
      if (j == 0) acc0 += t;
      else if (j == 1) acc1 += t;
      else if (j == 2) acc2 += t;
      else acc3 += t;
    }
  }
  float acc = (acc0 + acc1) + (acc2 + acc3);

  if (ih) red[rl] = acc;
  __syncthreads();
  if (!ih) out[(size_t)row * OUT_SZ + o] = acc + red[rl];
}

// ---- fallback (ws too small): exact raw-array kernel -----------------------
__global__ __launch_bounds__(512) void mlp_raw(
    const float* __restrict__ x,
    const float* __restrict__ w0, const float* __restrict__ b0,
    const float* __restrict__ w1, const float* __restrict__ b1,
    const float* __restrict__ w2, const float* __restrict__ b2,
    const float* __restrict__ ss, const float* __restrict__ rs,
    float* __restrict__ out) {
  __shared__ float red[256];
  const int tid  = threadIdx.x;
  const int wave = __builtin_amdgcn_readfirstlane(tid) >> 6;
  const int lane = tid & 63;
  const int half = wave >> 2;
  const int sub  = wave & 3;
  const int o     = blockIdx.x & (OUT_SZ - 1);
  const int chunk = blockIdx.x >> 7;
  const int b     = chunk * 256 + sub * 64 + lane;
  const int i0    = half * 64;
  const float4* __restrict__ xrow = (const float4*)(x + (size_t)b * IN_SZ + i0);
  float acc = 0.0f;
#pragma unroll 1
  for (int c = 0; c < 16; ++c) {
    float4 xv = xrow[c];
    float xs[4] = { xv.x, xv.y, xv.z, xv.w };
#pragma unroll
    for (int r = 0; r < 4; ++r) {
      int n = (i0 + c * 4 + r) * OUT_SZ + o;
      float h1[5], h2[5];
#pragma unroll
      for (int j = 0; j < 5; ++j)
        h1[j] = silu_f(fmaf(w0[n * 5 + j], xs[r], b0[n * 5 + j]));
#pragma unroll
      for (int j = 0; j < 5; ++j) {
        float z = b1[n * 5 + j];
#pragma unroll
        for (int k = 0; k < 5; ++k) z = fmaf(w1[n * 25 + j * 5 + k], h1[k], z);
        h2[j] = silu_f(z);
      }
      float y = b2[n];
#pragma unroll
      for (int k = 0; k < 5; ++k) y = fmaf(w2[n * 5 + k], h2[k], y);
      acc += fmaf(y, ss[n], xs[r] * rs[n]);
    }
  }
  if (half) red[sub * 64 + lane] = acc;
  __syncthreads();
  if (!half) out[(size_t)b * OUT_SZ + o] = acc + red[sub * 64 + lane];
}

extern "C" void kernel_launch(void* const* d_in, const int* in_sizes, int n_in,
                              void* d_out, int out_size, void* d_ws, size_t ws_size,
                              hipStream_t stream) {
  const float* x  = (const float*)d_in[0];
  const float* w0 = (const float*)d_in[1];
  const float* b0 = (const float*)d_in[2];
  const float* w1 = (const float*)d_in[3];
  const float* b1 = (const float*)d_in[4];
  const float* w2 = (const float*)d_in[5];
  const float* b2 = (const float*)d_in[6];
  const float* ss = (const float*)d_in[7];
  const float* rs = (const float*)d_in[8];

  const size_t TBL_BYTES = (size_t)NSUB * NSEG * sizeof(__half2);   // 6 MiB
  const size_t XT_BYTES  = (size_t)IN_SZ * BATCH * sizeof(float);   // 1 MiB

  if (ws_size >= TBL_BYTES + XT_BYTES) {
    __half2* tbl = (__half2*)d_ws;
    float4*  xTP = (float4*)((char*)d_ws + TBL_BYTES);
    prep<<<dim3(NSUB / 2 + 64), dim3(256), 0, stream>>>(
        x, w0, b0, w1, b1, w2, b2, ss, rs, tbl, xTP);
    mlp_tbl_lds<<<dim3(OUT_SZ * (BATCH / 256)), dim3(512), 0, stream>>>(
        xTP, tbl, (float*)d_out);
  } else {
    mlp_raw<<<dim3(OUT_SZ * (BATCH / 256)), dim3(512), 0, stream>>>(
        x, w0, b0, w1, b1, w2, b2, ss, rs, (float*)d_out);
  }
}

// Round 18
// 91.884 us; speedup vs baseline: 1.0492x; 1.0492x over previous
//
#include <hip/hip_runtime.h>
#include <hip/hip_fp16.h>

// MLPKANlayer: out[b][o] = sum_i g_n(x[b,i]), n = i*128+o,
//   g_n(x) = y_n(x)*ss_n + x*rs_n  (1->5->5->1 SiLU MLP). f32 in/out.
//
// R18: main kernel is VALU-ISSUE-bound (R14/R16/R17 all ~96us: TLP and VMEM
// changes neutral; ~10 VALU/eval * 33.5M evals = ~17us chip issue). Fix:
// amortize index math (depends only on (b,i), not o) across an OUTPUT PAIR:
// table interleaved ts[i][k][2] -> one ds_read_b64 serves both outputs;
// per-i cost ~14 VALU for 2 evals (~7/eval). NSEG=64 over [-4,4] keeps the
// pair table at 64 KiB LDS (h^2 error ~0.007 < 0.0225 threshold; |x|>4
// tails extrapolate linearly). Grid 256 blocks x 512 thr, float2 store.
// R13: table traffic stays in LDS. R15: no atomics. Floor ~63us is fixed.

constexpr int IN_SZ = 128, OUT_SZ = 128, BATCH = 2048, NSUB = IN_SZ * OUT_SZ;
constexpr int NSEG = 64;                       // segments; 65 knot values
constexpr float XMIN = -4.0f, XRANGE = 8.0f;
constexpr float STEP = XRANGE / (float)NSEG;   // 0.125
constexpr float INVH = (float)NSEG / XRANGE;   // 8
constexpr float UOFF = -XMIN * INVH;           // 32

__device__ __forceinline__ float silu_f(float z) {
  float t = __builtin_amdgcn_exp2f(z * -1.44269504088896f);   // exp(-z)
  return z * __builtin_amdgcn_rcpf(1.0f + t);
}

// ---- k1 prep: build pair-table (blocks < 8192) + pack-transpose x ----------
// Build: 2 subnets x 128 lanes (k = 0..64 active); subnet wave-uniform ->
// weights are s_loads. Entry: half2(g(x_k), g(x_{k+1})-g(x_k)) stored at
// tbl[(((o>>1)*128 + i)*64 + k)*2 + (o&1)]  (o-pair interleaved).
// Transpose: xTP[g][b][4] = x[b][4g..4g+3]  (float4-coalesced both sides).
__global__ __launch_bounds__(256) void prep(
    const float* __restrict__ x,
    const float* __restrict__ w0, const float* __restrict__ b0,
    const float* __restrict__ w1, const float* __restrict__ b1,
    const float* __restrict__ w2, const float* __restrict__ b2,
    const float* __restrict__ ss, const float* __restrict__ rs,
    __half2* __restrict__ tbl, float4* __restrict__ xTP) {
  __shared__ float smem[64 * 65];
  const int tid = threadIdx.x;
  const int blk = blockIdx.x;

  if (blk < NSUB / 2) {
    float (*gv)[128] = (float (*)[128])smem;
    const int sl = __builtin_amdgcn_readfirstlane(tid >> 7);  // 0..1 uniform
    const int k  = tid & 127;
    const int n  = blk * 2 + sl;

    if (k <= NSEG) {
      const float xk = XMIN + (float)k * STEP;
      float h1[5], h2[5];
#pragma unroll
      for (int j = 0; j < 5; ++j)
        h1[j] = silu_f(fmaf(w0[n * 5 + j], xk, b0[n * 5 + j]));
#pragma unroll
      for (int j = 0; j < 5; ++j) {
        float z = b1[n * 5 + j];
#pragma unroll
        for (int kk = 0; kk < 5; ++kk)
          z = fmaf(w1[n * 25 + j * 5 + kk], h1[kk], z);
        h2[j] = silu_f(z);
      }
      float y = b2[n];
#pragma unroll
      for (int kk = 0; kk < 5; ++kk) y = fmaf(w2[n * 5 + kk], h2[kk], y);
      gv[sl][k] = fmaf(y, ss[n], xk * rs[n]);
    }
    __syncthreads();
    if (k < NSEG) {
      float a = gv[sl][k];
      float s = gv[sl][k + 1] - a;
      int o = n & (OUT_SZ - 1), i = n >> 7;
      size_t idx = ((((size_t)(o >> 1) * IN_SZ) + i) * NSEG + k) * 2 + (o & 1);
      tbl[idx] = __floats2half2_rn(a, s);
    }
  } else {
    // pack-transpose: 64(b) x 64(i) tile
    float (*tile)[65] = (float (*)[65])smem;
    const int t   = blk - NSUB / 2;              // 0..63
    const int b0t = (t & 31) * 64;
    const int i0  = (t >> 5) * 64;
    const int l = tid & 63, w = tid >> 6;        // l = b-lane, w = 0..3
#pragma unroll
    for (int r = 0; r < 16; ++r) {
      int row = w + 4 * r;                       // b-local
      tile[row][l] = x[(size_t)(b0t + row) * IN_SZ + i0 + l];
    }
    __syncthreads();
#pragma unroll
    for (int r = 0; r < 4; ++r) {
      int g = w + 4 * r;                         // i-group local, 0..15
      float4 v = make_float4(tile[l][4 * g], tile[l][4 * g + 1],
                             tile[l][4 * g + 2], tile[l][4 * g + 3]);
      xTP[(size_t)(i0 / 4 + g) * BATCH + b0t + l] = v;
    }
  }
}

// ---- k2 main: block = (o-pair, 512 rows); 64 KiB LDS; b64 pair-gather ------
__global__ __launch_bounds__(512) void mlp_pair(
    const float4* __restrict__ xTP, const uint2* __restrict__ tbl,
    float* __restrict__ out) {
  __shared__ uint2 ts[IN_SZ * NSEG];   // 64 KiB: [i][k] -> (half2 o0, half2 o1)

  const int tid   = threadIdx.x;
  const int p     = blockIdx.x & 63;             // o-pair id
  const int chunk = blockIdx.x >> 6;             // 0..3

  // stage pair slab: 64 KiB = 4096 uint4, 8 per thread, coalesced
  {
    const uint4* __restrict__ s4 =
        (const uint4*)(tbl + (size_t)p * IN_SZ * NSEG);
    uint4* d4 = (uint4*)ts;
#pragma unroll
    for (int r = 0; r < 8; ++r) d4[tid + 512 * r] = s4[tid + 512 * r];
  }
  __syncthreads();

  const int row = chunk * 512 + tid;             // batch row
  const float4* __restrict__ xcol = xTP + row;

  float a0e = 0.0f, a0o = 0.0f, a1e = 0.0f, a1o = 0.0f;
#pragma unroll 4
  for (int g = 0; g < IN_SZ / 4; ++g) {
    float4 xv = xcol[(size_t)g * BATCH];         // 4 i-values, one dwordx4
    float xs[4] = { xv.x, xv.y, xv.z, xv.w };
#pragma unroll
    for (int j = 0; j < 4; ++j) {
      const int i = 4 * g + j;
      float u  = fmaf(xs[j], INVH, UOFF);
      float fi = __builtin_amdgcn_fmed3f(floorf(u), 0.0f, (float)(NSEG - 1));
      float f  = u - fi;                         // unclamped -> extrapolate
      uint2 hh = ts[i * NSEG + (int)fi];         // ds_read_b64: both outputs
      __half2 e0 = *(__half2*)&hh.x;
      __half2 e1 = *(__half2*)&hh.y;
      // fmaf(cvt(hi), f, acc + cvt(lo)) -> v_fma_mix candidates
      if (j & 1) {
        a0o = fmaf(__half2float(__high2half(e0)), f,
                   a0o + __half2float(__low2half(e0)));
        a1o = fmaf(__half2float(__high2half(e1)), f,
                   a1o + __half2float(__low2half(e1)));
      } else {
        a0e = fmaf(__half2float(__high2half(e0)), f,
                   a0e + __half2float(__low2half(e0)));
        a1e = fmaf(__half2float(__high2half(e1)), f,
                   a1e + __half2float(__low2half(e1)));
      }
    }
  }
  float2 res = make_float2(a0e + a0o, a1e + a1o);
  *(float2*)&out[(size_t)row * OUT_SZ + 2 * p] = res;
}

// ---- fallback (ws too small): exact raw-array kernel -----------------------
__global__ __launch_bounds__(512) void mlp_raw(
    const float* __restrict__ x,
    const float* __restrict__ w0, const float* __restrict__ b0,
    const float* __restrict__ w1, const float* __restrict__ b1,
    const float* __restrict__ w2, const float* __restrict__ b2,
    const float* __restrict__ ss, const float* __restrict__ rs,
    float* __restrict__ out) {
  __shared__ float red[256];
  const int tid  = threadIdx.x;
  const int wave = __builtin_amdgcn_readfirstlane(tid) >> 6;
  const int lane = tid & 63;
  const int half = wave >> 2;
  const int sub  = wave & 3;
  const int o     = blockIdx.x & (OUT_SZ - 1);
  const int chunk = blockIdx.x >> 7;
  const int b     = chunk * 256 + sub * 64 + lane;
  const int i0    = half * 64;
  const float4* __restrict__ xrow = (const float4*)(x + (size_t)b * IN_SZ + i0);
  float acc = 0.0f;
#pragma unroll 1
  for (int c = 0; c < 16; ++c) {
    float4 xv = xrow[c];
    float xs[4] = { xv.x, xv.y, xv.z, xv.w };
#pragma unroll
    for (int r = 0; r < 4; ++r) {
      int n = (i0 + c * 4 + r) * OUT_SZ + o;
      float h1[5], h2[5];
#pragma unroll
      for (int j = 0; j < 5; ++j)
        h1[j] = silu_f(fmaf(w0[n * 5 + j], xs[r], b0[n * 5 + j]));
#pragma unroll
      for (int j = 0; j < 5; ++j) {
        float z = b1[n * 5 + j];
#pragma unroll
        for (int k = 0; k < 5; ++k) z = fmaf(w1[n * 25 + j * 5 + k], h1[k], z);
        h2[j] = silu_f(z);
      }
      float y = b2[n];
#pragma unroll
      for (int k = 0; k < 5; ++k) y = fmaf(w2[n * 5 + k], h2[k], y);
      acc += fmaf(y, ss[n], xs[r] * rs[n]);
    }
  }
  if (half) red[sub * 64 + lane] = acc;
  __syncthreads();
  if (!half) out[(size_t)b * OUT_SZ + o] = acc + red[sub * 64 + lane];
}

extern "C" void kernel_launch(void* const* d_in, const int* in_sizes, int n_in,
                              void* d_out, int out_size, void* d_ws, size_t ws_size,
                              hipStream_t stream) {
  const float* x  = (const float*)d_in[0];
  const float* w0 = (const float*)d_in[1];
  const float* b0 = (const float*)d_in[2];
  const float* w1 = (const float*)d_in[3];
  const float* b1 = (const float*)d_in[4];
  const float* w2 = (const float*)d_in[5];
  const float* b2 = (const float*)d_in[6];
  const float* ss = (const float*)d_in[7];
  const float* rs = (const float*)d_in[8];

  const size_t TBL_BYTES = (size_t)NSUB * NSEG * sizeof(__half2);   // 4 MiB
  const size_t XT_BYTES  = (size_t)IN_SZ * BATCH * sizeof(float);   // 1 MiB

  if (ws_size >= TBL_BYTES + XT_BYTES) {
    __half2* tbl = (__half2*)d_ws;
    float4*  xTP = (float4*)((char*)d_ws + TBL_BYTES);
    prep<<<dim3(NSUB / 2 + 64), dim3(256), 0, stream>>>(
        x, w0, b0, w1, b1, w2, b2, ss, rs, tbl, xTP);
    mlp_pair<<<dim3(64 * (BATCH / 512)), dim3(512), 0, stream>>>(
        xTP, (const uint2*)tbl, (float*)d_out);
  } else {
    mlp_raw<<<dim3(OUT_SZ * (BATCH / 256)), dim3(512), 0, stream>>>(
        x, w0, b0, w1, b1, w2, b2, ss, rs, (float*)d_out);
  }
}

// Round 19
// 88.820 us; speedup vs baseline: 1.0854x; 1.0345x over previous
//
#include <hip/hip_runtime.h>
#include <hip/hip_fp16.h>

// MLPKANlayer: out[b][o] = sum_i g_n(x[b,i]), n = i*128+o,
//   g_n(x) = y_n(x)*ss_n + x*rs_n  (1->5->5->1 SiLU MLP). f32 in/out.
//
// R19 = R18's o-pair -> o-QUAD: index math (b,i-only) amortized over 4
// outputs; table ts[i][k][4 x half2] (NSEG=32 over [-4,4]) = exactly 64 KiB
// LDS; one ds_read_b128 per (b,i) serves 4 evals (~4 VALU/eval, was ~7).
// Evidence: R18 matched prediction (-3.7us) => VALU-issue-bound confirmed;
// absmax constant 0.0039 across h=0.094->0.125 => h^2 term sub-dominant,
// so h=0.25 is safe (predict ~0.006 vs 0.0225 threshold).
// Block = (o-quad, 256 rows) x 512 thr; waves 0-3 i<64, 4-7 i>=64; halves
// combine by reusing table LDS after a barrier. 256 blocks = 1/CU, 8 waves.
// R13: table stays in LDS. R15: no atomics. Harness floor ~63us is fixed.

constexpr int IN_SZ = 128, OUT_SZ = 128, BATCH = 2048, NSUB = IN_SZ * OUT_SZ;
constexpr int NSEG = 32;                       // segments; 33 knot values
constexpr float XMIN = -4.0f, XRANGE = 8.0f;
constexpr float STEP = XRANGE / (float)NSEG;   // 0.25
constexpr float INVH = (float)NSEG / XRANGE;   // 4
constexpr float UOFF = -XMIN * INVH;           // 16

__device__ __forceinline__ float silu_f(float z) {
  float t = __builtin_amdgcn_exp2f(z * -1.44269504088896f);   // exp(-z)
  return z * __builtin_amdgcn_rcpf(1.0f + t);
}

// ---- k1 prep: build quad-table (blocks < 4096) + pack-transpose x ----------
// Build: 4 subnets x 64 lanes (k = 0..32 active); subnet wave-uniform ->
// weights are s_loads. Entry half2(g(x_k), g(x_{k+1})-g(x_k)) stored at
// tbl[((((o>>2)*128 + i)*32 + k)*4 + (o&3)]  (o-quad interleaved).
// Transpose: xTP[g][b][4] = x[b][4g..4g+3]  (float4-coalesced both sides).
__global__ __launch_bounds__(256) void prep(
    const float* __restrict__ x,
    const float* __restrict__ w0, const float* __restrict__ b0,
    const float* __restrict__ w1, const float* __restrict__ b1,
    const float* __restrict__ w2, const float* __restrict__ b2,
    const float* __restrict__ ss, const float* __restrict__ rs,
    __half2* __restrict__ tbl, float4* __restrict__ xTP) {
  __shared__ float smem[64 * 65];
  const int tid = threadIdx.x;
  const int blk = blockIdx.x;

  if (blk < NSUB / 4) {
    float (*gv)[40] = (float (*)[40])smem;      // 4 subnets x 33 knots
    const int sl = __builtin_amdgcn_readfirstlane(tid >> 6);  // 0..3 uniform
    const int k  = tid & 63;
    const int n  = blk * 4 + sl;

    if (k <= NSEG) {
      const float xk = XMIN + (float)k * STEP;
      float h1[5], h2[5];
#pragma unroll
      for (int j = 0; j < 5; ++j)
        h1[j] = silu_f(fmaf(w0[n * 5 + j], xk, b0[n * 5 + j]));
#pragma unroll
      for (int j = 0; j < 5; ++j) {
        float z = b1[n * 5 + j];
#pragma unroll
        for (int kk = 0; kk < 5; ++kk)
          z = fmaf(w1[n * 25 + j * 5 + kk], h1[kk], z);
        h2[j] = silu_f(z);
      }
      float y = b2[n];
#pragma unroll
      for (int kk = 0; kk < 5; ++kk) y = fmaf(w2[n * 5 + kk], h2[kk], y);
      gv[sl][k] = fmaf(y, ss[n], xk * rs[n]);
    }
    __syncthreads();
    if (k < NSEG) {
      float a = gv[sl][k];
      float s = gv[sl][k + 1] - a;
      int o = n & (OUT_SZ - 1), i = n >> 7;
      size_t idx = ((((size_t)(o >> 2) * IN_SZ) + i) * NSEG + k) * 4 + (o & 3);
      tbl[idx] = __floats2half2_rn(a, s);
    }
  } else {
    // pack-transpose: 64(b) x 64(i) tile
    float (*tile)[65] = (float (*)[65])smem;
    const int t   = blk - NSUB / 4;              // 0..63
    const int b0t = (t & 31) * 64;
    const int i0  = (t >> 5) * 64;
    const int l = tid & 63, w = tid >> 6;        // l = b-lane, w = 0..3
#pragma unroll
    for (int r = 0; r < 16; ++r) {
      int row = w + 4 * r;                       // b-local
      tile[row][l] = x[(size_t)(b0t + row) * IN_SZ + i0 + l];
    }
    __syncthreads();
#pragma unroll
    for (int r = 0; r < 4; ++r) {
      int g = w + 4 * r;                         // i-group local, 0..15
      float4 v = make_float4(tile[l][4 * g], tile[l][4 * g + 1],
                             tile[l][4 * g + 2], tile[l][4 * g + 3]);
      xTP[(size_t)(i0 / 4 + g) * BATCH + b0t + l] = v;
    }
  }
}

// ---- k2 main: block = (o-quad, 256 rows); 64 KiB LDS; b128 quad-gather -----
__global__ __launch_bounds__(512) void mlp_quad(
    const float4* __restrict__ xTP, const uint4* __restrict__ tbl,
    float* __restrict__ out) {
  __shared__ uint4 ts[IN_SZ * NSEG];   // 64 KiB: [i][k] -> 4 x half2(a,s)

  const int tid   = threadIdx.x;
  const int q     = blockIdx.x & 31;             // o-quad id
  const int chunk = blockIdx.x >> 5;             // 0..7

  // stage quad slab: 64 KiB = 4096 uint4, 8 per thread, coalesced
  {
    const uint4* __restrict__ s4 = tbl + (size_t)q * IN_SZ * NSEG;
#pragma unroll
    for (int r = 0; r < 8; ++r) ts[tid + 512 * r] = s4[tid + 512 * r];
  }
  __syncthreads();

  const int rl  = tid & 255;                     // row-local, 0..255
  const int ih  = tid >> 8;                      // i-half (wave-uniform)
  const int row = chunk * 256 + rl;              // batch row
  const float4* __restrict__ xcol = xTP + (size_t)(ih * 16) * BATCH + row;

  float a0 = 0.0f, a1 = 0.0f, a2 = 0.0f, a3 = 0.0f;
#pragma unroll 4
  for (int g = 0; g < 16; ++g) {                 // 16 groups x 4 i = 64 evals
    float4 xv = xcol[(size_t)g * BATCH];         // 4 i-values, one dwordx4
    float xs[4] = { xv.x, xv.y, xv.z, xv.w };
#pragma unroll
    for (int j = 0; j < 4; ++j) {
      const int i = (ih * 16 + g) * 4 + j;       // absolute i
      float u  = fmaf(xs[j], INVH, UOFF);
      float fi = __builtin_amdgcn_fmed3f(floorf(u), 0.0f, (float)(NSEG - 1));
      float f  = u - fi;                         // unclamped -> extrapolate
      uint4 hh = ts[i * NSEG + (int)fi];         // ds_read_b128: 4 outputs
      __half2 e0 = *(__half2*)&hh.x;
      __half2 e1 = *(__half2*)&hh.y;
      __half2 e2 = *(__half2*)&hh.z;
      __half2 e3 = *(__half2*)&hh.w;
      a0 = fmaf(__half2float(__high2half(e0)), f, a0 + __half2float(__low2half(e0)));
      a1 = fmaf(__half2float(__high2half(e1)), f, a1 + __half2float(__low2half(e1)));
      a2 = fmaf(__half2float(__high2half(e2)), f, a2 + __half2float(__low2half(e2)));
      a3 = fmaf(__half2float(__high2half(e3)), f, a3 + __half2float(__low2half(e3)));
    }
  }

  // combine i-halves: reuse table LDS after all waves pass the barrier
  __syncthreads();
  float4* red = (float4*)ts;
  if (ih) red[rl] = make_float4(a0, a1, a2, a3);
  __syncthreads();
  if (!ih) {
    float4 r = red[rl];
    float4 res = make_float4(a0 + r.x, a1 + r.y, a2 + r.z, a3 + r.w);
    *(float4*)&out[(size_t)row * OUT_SZ + 4 * q] = res;
  }
}

// ---- fallback (ws too small): exact raw-array kernel -----------------------
__global__ __launch_bounds__(512) void mlp_raw(
    const float* __restrict__ x,
    const float* __restrict__ w0, const float* __restrict__ b0,
    const float* __restrict__ w1, const float* __restrict__ b1,
    const float* __restrict__ w2, const float* __restrict__ b2,
    const float* __restrict__ ss, const float* __restrict__ rs,
    float* __restrict__ out) {
  __shared__ float red[256];
  const int tid  = threadIdx.x;
  const int wave = __builtin_amdgcn_readfirstlane(tid) >> 6;
  const int lane = tid & 63;
  const int half = wave >> 2;
  const int sub  = wave & 3;
  const int o     = blockIdx.x & (OUT_SZ - 1);
  const int chunk = blockIdx.x >> 7;
  const int b     = chunk * 256 + sub * 64 + lane;
  const int i0    = half * 64;
  const float4* __restrict__ xrow = (const float4*)(x + (size_t)b * IN_SZ + i0);
  float acc = 0.0f;
#pragma unroll 1
  for (int c = 0; c < 16; ++c) {
    float4 xv = xrow[c];
    float xs[4] = { xv.x, xv.y, xv.z, xv.w };
#pragma unroll
    for (int r = 0; r < 4; ++r) {
      int n = (i0 + c * 4 + r) * OUT_SZ + o;
      float h1[5], h2[5];
#pragma unroll
      for (int j = 0; j < 5; ++j)
        h1[j] = silu_f(fmaf(w0[n * 5 + j], xs[r], b0[n * 5 + j]));
#pragma unroll
      for (int j = 0; j < 5; ++j) {
        float z = b1[n * 5 + j];
#pragma unroll
        for (int k = 0; k < 5; ++k) z = fmaf(w1[n * 25 + j * 5 + k], h1[k], z);
        h2[j] = silu_f(z);
      }
      float y = b2[n];
#pragma unroll
      for (int k = 0; k < 5; ++k) y = fmaf(w2[n * 5 + k], h2[k], y);
      acc += fmaf(y, ss[n], xs[r] * rs[n]);
    }
  }
  if (half) red[sub * 64 + lane] = acc;
  __syncthreads();
  if (!half) out[(size_t)b * OUT_SZ + o] = acc + red[sub * 64 + lane];
}

extern "C" void kernel_launch(void* const* d_in, const int* in_sizes, int n_in,
                              void* d_out, int out_size, void* d_ws, size_t ws_size,
                              hipStream_t stream) {
  const float* x  = (const float*)d_in[0];
  const float* w0 = (const float*)d_in[1];
  const float* b0 = (const float*)d_in[2];
  const float* w1 = (const float*)d_in[3];
  const float* b1 = (const float*)d_in[4];
  const float* w2 = (const float*)d_in[5];
  const float* b2 = (const float*)d_in[6];
  const float* ss = (const float*)d_in[7];
  const float* rs = (const float*)d_in[8];

  const size_t TBL_BYTES = (size_t)NSUB * NSEG * sizeof(__half2);   // 2 MiB
  const size_t XT_BYTES  = (size_t)IN_SZ * BATCH * sizeof(float);   // 1 MiB

  if (ws_size >= TBL_BYTES + XT_BYTES) {
    __half2* tbl = (__half2*)d_ws;
    float4*  xTP = (float4*)((char*)d_ws + TBL_BYTES);
    prep<<<dim3(NSUB / 4 + 64), dim3(256), 0, stream>>>(
        x, w0, b0, w1, b1, w2, b2, ss, rs, tbl, xTP);
    mlp_quad<<<dim3(32 * (BATCH / 256)), dim3(512), 0, stream>>>(
        xTP, (const uint4*)tbl, (float*)d_out);
  } else {
    mlp_raw<<<dim3(OUT_SZ * (BATCH / 256)), dim3(512), 0, stream>>>(
        x, w0, b0, w1, b1, w2, b2, ss, rs, (float*)d_out);
  }
}

// Round 20
// 86.568 us; speedup vs baseline: 1.1136x; 1.0260x over previous
//
#include <hip/hip_runtime.h>
#include <hip/hip_fp16.h>

// MLPKANlayer: out[b][o] = sum_i g_n(x[b,i]), n = i*128+o,
//   g_n(x) = y_n(x)*ss_n + x*rs_n  (1->5->5->1 SiLU MLP). f32 in/out.
//
// R20 = R19 (o-quad table, NSEG=32 over [-4,4], ds_read_b128 serves 4
// outputs, ~3.5 VALU/eval) + 2 blocks/CU: grid 512 (32 quads x 16 chunks of
// 128 rows); block = 512 thr = 128 rows x 4 i-quarters (wave-uniform iq).
// 64 KiB LDS x 2 resident = 128 KiB <= 160 -> staging/compute overlap across
// blocks, 16 waves/CU. 4 partials reduce via table-LDS reuse after barrier.
// Evidence: R18/R19 matched predictions (VALU-amortization lever). o-oct at
// NSEG=16 rejected: projected absmax ~0.028 > 0.0225. Harness floor ~63us.

constexpr int IN_SZ = 128, OUT_SZ = 128, BATCH = 2048, NSUB = IN_SZ * OUT_SZ;
constexpr int NSEG = 32;                       // segments; 33 knot values
constexpr float XMIN = -4.0f, XRANGE = 8.0f;
constexpr float STEP = XRANGE / (float)NSEG;   // 0.25
constexpr float INVH = (float)NSEG / XRANGE;   // 4
constexpr float UOFF = -XMIN * INVH;           // 16

__device__ __forceinline__ float silu_f(float z) {
  float t = __builtin_amdgcn_exp2f(z * -1.44269504088896f);   // exp(-z)
  return z * __builtin_amdgcn_rcpf(1.0f + t);
}

// ---- k1 prep: build quad-table (blocks < 4096) + pack-transpose x ----------
// Build: 4 subnets x 64 lanes (k = 0..32 active); subnet wave-uniform ->
// weights are s_loads. Entry half2(g(x_k), g(x_{k+1})-g(x_k)) stored at
// tbl[(((o>>2)*128 + i)*32 + k)*4 + (o&3)]  (o-quad interleaved).
// Transpose: xTP[g][b][4] = x[b][4g..4g+3]  (float4-coalesced both sides).
__global__ __launch_bounds__(256) void prep(
    const float* __restrict__ x,
    const float* __restrict__ w0, const float* __restrict__ b0,
    const float* __restrict__ w1, const float* __restrict__ b1,
    const float* __restrict__ w2, const float* __restrict__ b2,
    const float* __restrict__ ss, const float* __restrict__ rs,
    __half2* __restrict__ tbl, float4* __restrict__ xTP) {
  __shared__ float smem[64 * 65];
  const int tid = threadIdx.x;
  const int blk = blockIdx.x;

  if (blk < NSUB / 4) {
    float (*gv)[40] = (float (*)[40])smem;      // 4 subnets x 33 knots
    const int sl = __builtin_amdgcn_readfirstlane(tid >> 6);  // 0..3 uniform
    const int k  = tid & 63;
    const int n  = blk * 4 + sl;

    if (k <= NSEG) {
      const float xk = XMIN + (float)k * STEP;
      float h1[5], h2[5];
#pragma unroll
      for (int j = 0; j < 5; ++j)
        h1[j] = silu_f(fmaf(w0[n * 5 + j], xk, b0[n * 5 + j]));
#pragma unroll
      for (int j = 0; j < 5; ++j) {
        float z = b1[n * 5 + j];
#pragma unroll
        for (int kk = 0; kk < 5; ++kk)
          z = fmaf(w1[n * 25 + j * 5 + kk], h1[kk], z);
        h2[j] = silu_f(z);
      }
      float y = b2[n];
#pragma unroll
      for (int kk = 0; kk < 5; ++kk) y = fmaf(w2[n * 5 + kk], h2[kk], y);
      gv[sl][k] = fmaf(y, ss[n], xk * rs[n]);
    }
    __syncthreads();
    if (k < NSEG) {
      float a = gv[sl][k];
      float s = gv[sl][k + 1] - a;
      int o = n & (OUT_SZ - 1), i = n >> 7;
      size_t idx = ((((size_t)(o >> 2) * IN_SZ) + i) * NSEG + k) * 4 + (o & 3);
      tbl[idx] = __floats2half2_rn(a, s);
    }
  } else {
    // pack-transpose: 64(b) x 64(i) tile
    float (*tile)[65] = (float (*)[65])smem;
    const int t   = blk - NSUB / 4;              // 0..63
    const int b0t = (t & 31) * 64;
    const int i0  = (t >> 5) * 64;
    const int l = tid & 63, w = tid >> 6;        // l = b-lane, w = 0..3
#pragma unroll
    for (int r = 0; r < 16; ++r) {
      int row = w + 4 * r;                       // b-local
      tile[row][l] = x[(size_t)(b0t + row) * IN_SZ + i0 + l];
    }
    __syncthreads();
#pragma unroll
    for (int r = 0; r < 4; ++r) {
      int g = w + 4 * r;                         // i-group local, 0..15
      float4 v = make_float4(tile[l][4 * g], tile[l][4 * g + 1],
                             tile[l][4 * g + 2], tile[l][4 * g + 3]);
      xTP[(size_t)(i0 / 4 + g) * BATCH + b0t + l] = v;
    }
  }
}

// ---- k2 main: block = (o-quad, 128 rows) x 512 thr = 4 i-quarters ----------
__global__ __launch_bounds__(512) void mlp_quad(
    const float4* __restrict__ xTP, const uint4* __restrict__ tbl,
    float* __restrict__ out) {
  __shared__ uint4 ts[IN_SZ * NSEG];   // 64 KiB: [i][k] -> 4 x half2(a,s)

  const int tid   = threadIdx.x;
  const int q     = blockIdx.x & 31;             // o-quad id
  const int chunk = blockIdx.x >> 5;             // 0..15 (128 rows each)

  // stage quad slab: 64 KiB = 4096 uint4, 8 per thread, coalesced
  {
    const uint4* __restrict__ s4 = tbl + (size_t)q * IN_SZ * NSEG;
#pragma unroll
    for (int r = 0; r < 8; ++r) ts[tid + 512 * r] = s4[tid + 512 * r];
  }
  __syncthreads();

  const int rl  = tid & 127;                     // row-local, 0..127
  const int iq  = tid >> 7;                      // i-quarter (wave-uniform)
  const int row = chunk * 128 + rl;              // batch row
  const float4* __restrict__ xcol = xTP + (size_t)(iq * 8) * BATCH + row;

  float a0 = 0.0f, a1 = 0.0f, a2 = 0.0f, a3 = 0.0f;
#pragma unroll 4
  for (int g = 0; g < 8; ++g) {                  // 8 groups x 4 i = 32 evals
    float4 xv = xcol[(size_t)g * BATCH];         // 4 i-values, one dwordx4
    float xs[4] = { xv.x, xv.y, xv.z, xv.w };
#pragma unroll
    for (int j = 0; j < 4; ++j) {
      const int i = (iq * 8 + g) * 4 + j;        // absolute i
      float u  = fmaf(xs[j], INVH, UOFF);
      float fi = __builtin_amdgcn_fmed3f(floorf(u), 0.0f, (float)(NSEG - 1));
      float f  = u - fi;                         // unclamped -> extrapolate
      uint4 hh = ts[i * NSEG + (int)fi];         // ds_read_b128: 4 outputs
      __half2 e0 = *(__half2*)&hh.x;
      __half2 e1 = *(__half2*)&hh.y;
      __half2 e2 = *(__half2*)&hh.z;
      __half2 e3 = *(__half2*)&hh.w;
      a0 = fmaf(__half2float(__high2half(e0)), f, a0 + __half2float(__low2half(e0)));
      a1 = fmaf(__half2float(__high2half(e1)), f, a1 + __half2float(__low2half(e1)));
      a2 = fmaf(__half2float(__high2half(e2)), f, a2 + __half2float(__low2half(e2)));
      a3 = fmaf(__half2float(__high2half(e3)), f, a3 + __half2float(__low2half(e3)));
    }
  }

  // combine 4 i-quarters: reuse table LDS after all waves pass the barrier
  __syncthreads();
  float4* red = (float4*)ts;                     // [3][128] partials
  if (iq) red[(iq - 1) * 128 + rl] = make_float4(a0, a1, a2, a3);
  __syncthreads();
  if (!iq) {
    float4 r1 = red[rl], r2 = red[128 + rl], r3 = red[256 + rl];
    float4 res = make_float4(a0 + r1.x + r2.x + r3.x,
                             a1 + r1.y + r2.y + r3.y,
                             a2 + r1.z + r2.z + r3.z,
                             a3 + r1.w + r2.w + r3.w);
    *(float4*)&out[(size_t)row * OUT_SZ + 4 * q] = res;
  }
}

// ---- fallback (ws too small): exact raw-array kernel -----------------------
__global__ __launch_bounds__(512) void mlp_raw(
    const float* __restrict__ x,
    const float* __restrict__ w0, const float* __restrict__ b0,
    const float* __restrict__ w1, const float* __restrict__ b1,
    const float* __restrict__ w2, const float* __restrict__ b2,
    const float* __restrict__ ss, const float* __restrict__ rs,
    float* __restrict__ out) {
  __shared__ float red[256];
  const int tid  = threadIdx.x;
  const int wave = __builtin_amdgcn_readfirstlane(tid) >> 6;
  const int lane = tid & 63;
  const int half = wave >> 2;
  const int sub  = wave & 3;
  const int o     = blockIdx.x & (OUT_SZ - 1);
  const int chunk = blockIdx.x >> 7;
  const int b     = chunk * 256 + sub * 64 + lane;
  const int i0    = half * 64;
  const float4* __restrict__ xrow = (const float4*)(x + (size_t)b * IN_SZ + i0);
  float acc = 0.0f;
#pragma unroll 1
  for (int c = 0; c < 16; ++c) {
    float4 xv = xrow[c];
    float xs[4] = { xv.x, xv.y, xv.z, xv.w };
#pragma unroll
    for (int r = 0; r < 4; ++r) {
      int n = (i0 + c * 4 + r) * OUT_SZ + o;
      float h1[5], h2[5];
#pragma unroll
      for (int j = 0; j < 5; ++j)
        h1[j] = silu_f(fmaf(w0[n * 5 + j], xs[r], b0[n * 5 + j]));
#pragma unroll
      for (int j = 0; j < 5; ++j) {
        float z = b1[n * 5 + j];
#pragma unroll
        for (int k = 0; k < 5; ++k) z = fmaf(w1[n * 25 + j * 5 + k], h1[k], z);
        h2[j] = silu_f(z);
      }
      float y = b2[n];
#pragma unroll
      for (int k = 0; k < 5; ++k) y = fmaf(w2[n * 5 + k], h2[k], y);
      acc += fmaf(y, ss[n], xs[r] * rs[n]);
    }
  }
  if (half) red[sub * 64 + lane] = acc;
  __syncthreads();
  if (!half) out[(size_t)b * OUT_SZ + o] = acc + red[sub * 64 + lane];
}

extern "C" void kernel_launch(void* const* d_in, const int* in_sizes, int n_in,
                              void* d_out, int out_size, void* d_ws, size_t ws_size,
                              hipStream_t stream) {
  const float* x  = (const float*)d_in[0];
  const float* w0 = (const float*)d_in[1];
  const float* b0 = (const float*)d_in[2];
  const float* w1 = (const float*)d_in[3];
  const float* b1 = (const float*)d_in[4];
  const float* w2 = (const float*)d_in[5];
  const float* b2 = (const float*)d_in[6];
  const float* ss = (const float*)d_in[7];
  const float* rs = (const float*)d_in[8];

  const size_t TBL_BYTES = (size_t)NSUB * NSEG * sizeof(__half2);   // 2 MiB
  const size_t XT_BYTES  = (size_t)IN_SZ * BATCH * sizeof(float);   // 1 MiB

  if (ws_size >= TBL_BYTES + XT_BYTES) {
    __half2* tbl = (__half2*)d_ws;
    float4*  xTP = (float4*)((char*)d_ws + TBL_BYTES);
    prep<<<dim3(NSUB / 4 + 64), dim3(256), 0, stream>>>(
        x, w0, b0, w1, b1, w2, b2, ss, rs, tbl, xTP);
    mlp_quad<<<dim3(32 * (BATCH / 128)), dim3(512), 0, stream>>>(
        xTP, (const uint4*)tbl, (float*)d_out);
  } else {
    mlp_raw<<<dim3(OUT_SZ * (BATCH / 256)), dim3(512), 0, stream>>>(
        x, w0, b0, w1, b1, w2, b2, ss, rs, (float*)d_out);
  }
}